// Round 5
// baseline (1079.325 us; speedup 1.0000x reference)
//
#include <hip/hip_runtime.h>
#include <cstdint>

typedef __attribute__((ext_vector_type(8))) short short8;
typedef __attribute__((ext_vector_type(4))) float f32x4;
typedef __attribute__((ext_vector_type(4))) unsigned u32x4;

#define R_DIM 1024
#define KE    1056      // 1024 state + 8 x + 24 zero pad
#define T_LEN 65536
#define CCH   2048      // chunks (columns of the batched recurrence)
#define LCH   32        // real steps per chunk
#define WARM  16        // warmup steps (absmax flat 64->32->24 => big margin)
#define STEPS (WARM + LCH)   // 48
#define NGRP  64        // independent groups, 32 cols each
#define WGC   32        // cols per WG (= per group)
#define RWG   8         // row-WGs per group (128 rows each)

static __device__ __forceinline__ unsigned short f2bf(float f){
  unsigned u = __builtin_bit_cast(unsigned, f);
  u += 0x7fffu + ((u >> 16) & 1u);
  return (unsigned short)(u >> 16);
}
static __device__ __forceinline__ float fast_tanh(float x){
  float e = __expf(2.0f * x);          // inf/0 saturate correctly to +/-1
  return 1.0f - 2.0f / (e + 1.0f);
}

// ---- prep: W_ext = [W_res | W_in | 0] in bf16, row-major [1024][1056] ----
// zeros at k>=1032 are LOAD-BEARING: they null garbage in B pad region.
__global__ void k_build_wext(const float* __restrict__ Wres,
                             const float* __restrict__ Win,
                             short* __restrict__ Wext){
  int idx = blockIdx.x * 256 + threadIdx.x;       // 1024*1056 = 4224*256
  int r = idx / KE, k = idx % KE;
  float v = 0.0f;
  if (k < 1024)      v = Wres[(size_t)r * 1024 + k];
  else if (k < 1032) v = Win[r * 8 + (k - 1024)];
  Wext[idx] = (short)f2bf(v);
}

// ---- prep: zero the state region [0,1024) of each chunk's initial-read row ----
// (HIST: hist slot +1 of each chunk; !HIST: S0 rows). Pad region may stay
// poisoned: A-zeros at k>=1032 null it in the MFMA.
__global__ void k_zero_init(short* __restrict__ base, size_t rowstride){
  int idx = blockIdx.x * 256 + threadIdx.x;   // 2048 rows x 512 dwords
  int c = idx >> 9, d = idx & 511;
  ((unsigned*)(base + (size_t)c * rowstride))[d] = 0u;
}

// ---- prep: x-slot of each chunk's initial row, zero flags ----
__global__ void k_init_x(const float* __restrict__ in, short* __restrict__ x0,
                         size_t rowstride, unsigned* __restrict__ cnt){
  int c = blockIdx.x * 256 + threadIdx.x;
  if (c < NGRP * 16) cnt[c] = 0u;             // 64 groups x 8 flags (16-dw stride)
  if (c < CCH){
    int t0 = c * LCH - WARM;
    uint4 xv = {0,0,0,0};
    if (t0 >= 0){
      const float4 A4 = *(const float4*)(in + (size_t)t0 * 8);
      const float4 B4 = *(const float4*)(in + (size_t)t0 * 8 + 4);
      xv.x = f2bf(A4.x) | ((unsigned)f2bf(A4.y) << 16);
      xv.y = f2bf(A4.z) | ((unsigned)f2bf(A4.w) << 16);
      xv.z = f2bf(B4.x) | ((unsigned)f2bf(B4.y) << 16);
      xv.w = f2bf(B4.z) | ((unsigned)f2bf(B4.w) << 16);
    }
    *(uint4*)(x0 + (size_t)c * rowstride) = xv;
  }
}

// ---- output rows 1024..1031 = inputs^T (exact fp32 copy) ----
__global__ void k_xrows(const float* __restrict__ in, float* __restrict__ out){
  int t = blockIdx.x * 256 + threadIdx.x;
  const float4 a = *(const float4*)(in + (size_t)t * 8);
  const float4 b = *(const float4*)(in + (size_t)t * 8 + 4);
  out[(size_t)(R_DIM + 0) * T_LEN + t] = a.x;
  out[(size_t)(R_DIM + 1) * T_LEN + t] = a.y;
  out[(size_t)(R_DIM + 2) * T_LEN + t] = a.z;
  out[(size_t)(R_DIM + 3) * T_LEN + t] = a.w;
  out[(size_t)(R_DIM + 4) * T_LEN + t] = b.x;
  out[(size_t)(R_DIM + 5) * T_LEN + t] = b.y;
  out[(size_t)(R_DIM + 6) * T_LEN + t] = b.z;
  out[(size_t)(R_DIM + 7) * T_LEN + t] = b.w;
}

// ---- hist[t][r] (bf16) -> out[r][t] (f32), tiled transpose ----
__global__ void k_transpose(const short* __restrict__ hist, float* __restrict__ out){
  __shared__ float tile[64][65];
  const int t0 = blockIdx.x * 64;
  const int r0 = blockIdx.y * 64;
  for (int it = 0; it < 2; ++it){
    int id = it * 256 + threadIdx.x;     // 512 chunks of 8 bf16
    int tr = id >> 3;
    int c8 = (id & 7) * 8;
    short8 v = *(const short8*)(hist + (size_t)(t0 + tr) * KE + r0 + c8);
    #pragma unroll
    for (int j = 0; j < 8; ++j){
      unsigned u = ((unsigned)(unsigned short)v[j]) << 16;
      tile[tr][c8 + j] = __builtin_bit_cast(float, u);
    }
  }
  __syncthreads();
  #pragma unroll
  for (int p = 0; p < 16; ++p){
    int rr = (threadIdx.x >> 6) + p * 4;
    int tc = threadIdx.x & 63;
    out[(size_t)(r0 + rr) * T_LEN + t0 + tc] = tile[tc][rr];
  }
}

// ---- main stepped kernel: 512 WGs x 512 thr (2 WGs/CU); WG = 128 rows x 32 cols.
// bid = g*8 + rwg: resident prefixes contain only COMPLETE groups (deadlock-safe);
// co-resident WGs (bid, bid+256) are different groups -> phase overlap.
// A (weights) in VGPRs, K split across wave pairs. All cross-WG data via
// sc0/sc1 coherence-point accesses; fence-free flag sync (no atomics, no
// cache maintenance). Warmup state ping-pongs in each chunk's hist rows
// (slot +1 then alternating), so no separate S buffers when HIST.
template<bool HIST>
__global__ __launch_bounds__(512, 4)
void k_esn(const float* __restrict__ inputs, const short* __restrict__ Wext,
           short* __restrict__ S0, short* __restrict__ S1,
           short* __restrict__ hist, unsigned* __restrict__ cnt,
           float* __restrict__ out)
{
  __shared__ __align__(16) char lds[65536];   // 32 cols x 2048B (k<1024), XOR-swizzled
  const int tid  = threadIdx.x;
  const int g    = blockIdx.x >> 3;
  const int rwg  = blockIdx.x & 7;
  const int wv   = tid >> 6;                  // 0..7
  const int lane = tid & 63;
  const int l15  = lane & 15, l4 = lane >> 4;
  const int hi   = wv & 1;                    // K-half of this wave
  const int rbase = rwg * 128 + (wv >> 1) * 32;
  const int colbase = g * WGC;
  unsigned* gflags = cnt + g * 16;            // 8 dword flags in one 64B line

  // read-row for step k: state s_{k-1} input. warmup parity: read slot (k+1)&1.
  auto browf = [&](int col, int k) -> const short* {
    if (HIST){
      size_t row = (k <= WARM) ? ((size_t)col * LCH + ((k + 1) & 1))
                               : ((size_t)col * LCH + (size_t)(k - WARM) - 1);
      return hist + row * KE;
    }
    return ((k & 1) ? S1 : S0) + (size_t)col * KE;
  };
  // write-row for step k's output (state consumed by step k+1)
  auto wrowf = [&](int col, int k) -> short* {
    if (HIST){
      size_t row = (k < WARM) ? ((size_t)col * LCH + (k & 1))
                              : ((size_t)col * LCH + (size_t)(k - WARM));
      return hist + row * KE;
    }
    return ((k & 1) ? S0 : S1) + (size_t)col * KE;
  };

  // ---- loop-invariant A fragments in registers ----
  // hi=0: kk 0..16 (17 frags); hi=1: kk 17..32 (16 frags; kk32 = global-B tail)
  const int NA = hi ? 16 : 17;
  const int KB = hi ? 17 : 0;
  const int NL = hi ? 15 : 17;   // frags consumed from LDS
  short8 a0[17], a1[17];
  {
    const short* abase = Wext + (size_t)(rbase + l15) * KE + l4 * 8;
    #pragma unroll
    for (int i = 0; i < 17; ++i){
      if (i < NA){
        const short* ap = abase + (KB + i) * 32;
        a0[i] = *(const short8*)ap;
        a1[i] = *(const short8*)(ap + (size_t)16 * KE);
      }
    }
  }

  // staging geometry: thread owns col (tid>>4), 8 chunks of 16B spaced 256B
  const int scol = tid >> 4;
  const int skb0 = (tid & 15) << 4;
  const int sswz = (scol & 7) << 4;
  // B-frag read geometry
  const int colb0 = l15 * 2048;
  const int bswz  = (l15 & 7) << 4;
  const int l4b   = l4 * 16;
  // exchange geometry: conflict-free octets (bits[6:4] = (lane&7)^(lane>>3))
  const int xsw = (lane * 16) ^ ((lane >> 3) << 4);

  for (int k = 0; k < STEPS; ++k){
    // ---- wait for all 8 producers of this group (fence-free flag poll) ----
    if (k > 0){
      if (wv == 0){
        const unsigned* fp = gflags + (lane & 7);
        int guard = 0;
        for (;;){
          unsigned v;
          asm volatile("global_load_dword %0, %1, off sc0 sc1\n\t"
                       "s_waitcnt vmcnt(0)"
                       : "=v"(v) : "v"(fp) : "memory");
          if (!__any((int)(v < (unsigned)k))) break;
          __builtin_amdgcn_s_sleep(1);
          if (++guard > 1000000) break;      // failsafe: degrade, don't hang
        }
      }
      __syncthreads();                        // A
    }

    // ---- K-ext tail B loads first (latency overlaps staging) ----
    unsigned long long t00=0, t01=0, t10=0, t11=0;
    if (hi){
      const unsigned long long* tp0 =
        (const unsigned long long*)(browf(colbase + l15, k) + 1024 + l4 * 8);
      const unsigned long long* tp1 =
        (const unsigned long long*)(browf(colbase + 16 + l15, k) + 1024 + l4 * 8);
      t00 = __hip_atomic_load(tp0,     __ATOMIC_RELAXED, __HIP_MEMORY_SCOPE_AGENT);
      t01 = __hip_atomic_load(tp0 + 1, __ATOMIC_RELAXED, __HIP_MEMORY_SCOPE_AGENT);
      t10 = __hip_atomic_load(tp1,     __ATOMIC_RELAXED, __HIP_MEMORY_SCOPE_AGENT);
      t11 = __hip_atomic_load(tp1 + 1, __ATOMIC_RELAXED, __HIP_MEMORY_SCOPE_AGENT);
    }

    // ---- stage B (k<1024) into LDS; sc0/sc1 = read at coherence point ----
    {
      const short* srow = browf(colbase + scol, k);
      const char* sp = (const char*)srow + skb0;
      u32x4 r0,r1,r2,r3,r4,r5,r6,r7;
      asm volatile(
        "global_load_dwordx4 %0, %8, off sc0 sc1\n\t"
        "global_load_dwordx4 %1, %8, off offset:256 sc0 sc1\n\t"
        "global_load_dwordx4 %2, %8, off offset:512 sc0 sc1\n\t"
        "global_load_dwordx4 %3, %8, off offset:768 sc0 sc1\n\t"
        "global_load_dwordx4 %4, %8, off offset:1024 sc0 sc1\n\t"
        "global_load_dwordx4 %5, %8, off offset:1280 sc0 sc1\n\t"
        "global_load_dwordx4 %6, %8, off offset:1536 sc0 sc1\n\t"
        "global_load_dwordx4 %7, %8, off offset:1792 sc0 sc1\n\t"
        "s_waitcnt vmcnt(0)"
        : "=&v"(r0),"=&v"(r1),"=&v"(r2),"=&v"(r3),
          "=&v"(r4),"=&v"(r5),"=&v"(r6),"=&v"(r7)
        : "v"(sp) : "memory");
      char* dst = &lds[scol * 2048];
      *(u32x4*)(dst + ((skb0 +    0) ^ sswz)) = r0;
      *(u32x4*)(dst + ((skb0 +  256) ^ sswz)) = r1;
      *(u32x4*)(dst + ((skb0 +  512) ^ sswz)) = r2;
      *(u32x4*)(dst + ((skb0 +  768) ^ sswz)) = r3;
      *(u32x4*)(dst + ((skb0 + 1024) ^ sswz)) = r4;
      *(u32x4*)(dst + ((skb0 + 1280) ^ sswz)) = r5;
      *(u32x4*)(dst + ((skb0 + 1536) ^ sswz)) = r6;
      *(u32x4*)(dst + ((skb0 + 1792) ^ sswz)) = r7;
    }
    __syncthreads();                          // B

    // ---- MFMA K-loop (A from regs, B from LDS) ----
    f32x4 acc00 = {0,0,0,0}, acc01 = {0,0,0,0}, acc10 = {0,0,0,0}, acc11 = {0,0,0,0};
    #pragma unroll
    for (int i = 0; i < 17; ++i){
      if (i < NL){
        int kb = (KB + i) * 64 + l4b;
        const short8 b0 = *(const short8*)(&lds[colb0 + ((kb) ^ bswz)]);
        const short8 b1 = *(const short8*)(&lds[colb0 + 32768 + ((kb) ^ bswz)]);
        acc00 = __builtin_amdgcn_mfma_f32_16x16x32_bf16(a0[i], b0, acc00, 0, 0, 0);
        acc01 = __builtin_amdgcn_mfma_f32_16x16x32_bf16(a0[i], b1, acc01, 0, 0, 0);
        acc10 = __builtin_amdgcn_mfma_f32_16x16x32_bf16(a1[i], b0, acc10, 0, 0, 0);
        acc11 = __builtin_amdgcn_mfma_f32_16x16x32_bf16(a1[i], b1, acc11, 0, 0, 0);
      }
    }
    if (hi){   // kk=32 tail: A index 15, B from registers (pad nulled by Wext zeros)
      u32x4 v0; v0.x=(unsigned)t00; v0.y=(unsigned)(t00>>32); v0.z=(unsigned)t01; v0.w=(unsigned)(t01>>32);
      u32x4 v1; v1.x=(unsigned)t10; v1.y=(unsigned)(t10>>32); v1.z=(unsigned)t11; v1.w=(unsigned)(t11>>32);
      const short8 b0 = __builtin_bit_cast(short8, v0);
      const short8 b1 = __builtin_bit_cast(short8, v1);
      acc00 = __builtin_amdgcn_mfma_f32_16x16x32_bf16(a0[15], b0, acc00, 0, 0, 0);
      acc01 = __builtin_amdgcn_mfma_f32_16x16x32_bf16(a0[15], b1, acc01, 0, 0, 0);
      acc10 = __builtin_amdgcn_mfma_f32_16x16x32_bf16(a1[15], b0, acc10, 0, 0, 0);
      acc11 = __builtin_amdgcn_mfma_f32_16x16x32_bf16(a1[15], b1, acc11, 0, 0, 0);
    }

    // ---- cross-pair K-reduction via LDS (reuse B region after barrier) ----
    __syncthreads();                          // C
    {
      f32x4 wA = hi ? acc00 : acc10;          // this wave's OTHER row-tile partials
      f32x4 wB = hi ? acc01 : acc11;
      *(f32x4*)(&lds[wv * 1024 + xsw])        = wA;
      *(f32x4*)(&lds[8192 + wv * 1024 + xsw]) = wB;
    }
    __syncthreads();                          // D
    {
      f32x4 p0 = *(const f32x4*)(&lds[(wv ^ 1) * 1024 + xsw]);
      f32x4 p1 = *(const f32x4*)(&lds[8192 + (wv ^ 1) * 1024 + xsw]);
      f32x4 f0 = (hi ? acc10 : acc00) + p0;   // own row-tile + partner's partial
      f32x4 f1 = (hi ? acc11 : acc01) + p1;
      const int rowb = rbase + hi * 16 + l4 * 4;
      #pragma unroll
      for (int ct = 0; ct < 2; ++ct){
        f32x4 z = ct ? f1 : f0;
        float s0 = fast_tanh(z[0]), s1 = fast_tanh(z[1]);
        float s2 = fast_tanh(z[2]), s3 = fast_tanh(z[3]);
        unsigned long long pk = (unsigned long long)f2bf(s0)
          | ((unsigned long long)f2bf(s1) << 16)
          | ((unsigned long long)f2bf(s2) << 32)
          | ((unsigned long long)f2bf(s3) << 48);
        int col = colbase + ct * 16 + l15;
        short* wp = wrowf(col, k) + rowb;
        asm volatile("global_store_dwordx2 %0, %1, off sc0 sc1"
                     :: "v"(wp), "v"(pk) : "memory");
        if (!HIST && k >= WARM){
          int tk = col * LCH + k - WARM;
          float* op = out + (size_t)rowb * T_LEN + tk;
          op[0] = s0; op[(size_t)T_LEN] = s1;
          op[(size_t)2 * T_LEN] = s2; op[(size_t)3 * T_LEN] = s3;
        }
      }
    }

    // ---- x for next step (one WG per group) ----
    if (rwg == 0 && tid < WGC && (k + 1) < STEPS){
      int col = colbase + tid;
      short* xr = wrowf(col, k) + 1024;
      int tn = col * LCH + (k + 1) - WARM;
      u32x4 xv = {0,0,0,0};
      if (tn >= 0){
        const float4 A4 = *(const float4*)(inputs + (size_t)tn * 8);
        const float4 B4 = *(const float4*)(inputs + (size_t)tn * 8 + 4);
        xv.x = f2bf(A4.x) | ((unsigned)f2bf(A4.y) << 16);
        xv.y = f2bf(A4.z) | ((unsigned)f2bf(A4.w) << 16);
        xv.z = f2bf(B4.x) | ((unsigned)f2bf(B4.y) << 16);
        xv.w = f2bf(B4.z) | ((unsigned)f2bf(B4.w) << 16);
      }
      asm volatile("global_store_dwordx4 %0, %1, off sc0 sc1"
                   :: "v"(xr), "v"(xv) : "memory");
    }

    // ---- drain own stores to coherence point, then signal via flag ----
    asm volatile("s_waitcnt vmcnt(0)" ::: "memory");
    __syncthreads();                          // E (all waves drained)
    if (tid == 0 && (k + 1) < STEPS){
      unsigned* fw = gflags + rwg;
      unsigned fv = (unsigned)(k + 1);
      asm volatile("global_store_dword %0, %1, off sc0 sc1"
                   :: "v"(fw), "v"(fv) : "memory");
    }
  }
}

extern "C" void kernel_launch(void* const* d_in, const int* in_sizes, int n_in,
                              void* d_out, int out_size, void* d_ws, size_t ws_size,
                              hipStream_t stream)
{
  (void)in_sizes; (void)n_in; (void)out_size;
  const float* inputs = (const float*)d_in[0];
  const float* Win    = (const float*)d_in[1];
  const float* Wres   = (const float*)d_in[2];
  float* out = (float*)d_out;
  char* ws = (char*)d_ws;

  short*    Wext = (short*)(ws);                       // 2,162,688 B
  unsigned* cnt  = (unsigned*)(ws + 2162688);          // 64 groups x 64B = 4,096 B
  char*     data = ws + 2166784;
  short*    hist = (short*)data;                       // 65536*1056*2 = 138,412,032 B
  short*    S0   = (short*)data;                       // !HIST: 2048*1056*2 = 4,325,376 B
  short*    S1   = (short*)(data + 4325376);
  const bool hist_ok = ws_size >= (2166784ull + 138412032ull);

  hipLaunchKernelGGL(k_build_wext, dim3(4224), dim3(256), 0, stream, Wres, Win, Wext);
  hipLaunchKernelGGL(k_xrows,      dim3(256),  dim3(256), 0, stream, inputs, out);
  if (hist_ok){
    // zero state region of each chunk's warmup slot (+1 row), x into it, flags=0
    hipLaunchKernelGGL(k_zero_init, dim3(4096), dim3(256), 0, stream,
                       hist + KE, (size_t)LCH * KE);
    hipLaunchKernelGGL(k_init_x,    dim3(8),    dim3(256), 0, stream,
                       inputs, hist + KE + 1024, (size_t)LCH * KE, cnt);
    hipLaunchKernelGGL((k_esn<true>),  dim3(RWG * NGRP), dim3(512), 0, stream,
                       inputs, Wext, S0, S1, hist, cnt, out);
    hipLaunchKernelGGL(k_transpose, dim3(1024, 16), dim3(256), 0, stream, hist, out);
  } else {
    hipLaunchKernelGGL(k_zero_init, dim3(4096), dim3(256), 0, stream,
                       S0, (size_t)KE);
    hipLaunchKernelGGL(k_init_x,    dim3(8),    dim3(256), 0, stream,
                       inputs, S0 + 1024, (size_t)KE, cnt);
    hipLaunchKernelGGL((k_esn<false>), dim3(RWG * NGRP), dim3(512), 0, stream,
                       inputs, Wext, S0, S1, hist, cnt, out);
  }
}

// Round 6
// 677.088 us; speedup vs baseline: 1.5941x; 1.5941x over previous
//
#include <hip/hip_runtime.h>
#include <cstdint>

typedef __attribute__((ext_vector_type(8))) short short8;
typedef __attribute__((ext_vector_type(4))) float f32x4;
typedef __attribute__((ext_vector_type(4))) unsigned u32x4;

#define R_DIM 1024
#define KE    1056      // 1024 state + 8 x + 24 zero pad
#define T_LEN 65536
#define CCH   2048      // chunks (columns of the batched recurrence)
#define LCH   32        // real steps per chunk
#define WARM  16        // warmup steps (absmax flat 64->32->24->16 => at bf16 floor)
#define STEPS (WARM + LCH)   // 48
#define NGRP  32        // independent groups, 64 cols each
#define WGC   64        // cols per WG (= per group)
#define RWG   8         // row-WGs per group (128 rows each)
#define LDSB  131072    // 64 cols x 2048B staged B (dynamic LDS)

static __device__ __forceinline__ unsigned short f2bf(float f){
  unsigned u = __builtin_bit_cast(unsigned, f);
  u += 0x7fffu + ((u >> 16) & 1u);
  return (unsigned short)(u >> 16);
}
static __device__ __forceinline__ float fast_tanh(float x){
  float e = __expf(2.0f * x);          // inf/0 saturate correctly to +/-1
  return 1.0f - 2.0f / (e + 1.0f);
}

// ---- prep: W_ext = [W_res | W_in | 0] in bf16, row-major [1024][1056] ----
// zeros at k>=1032 are LOAD-BEARING: they null garbage in B pad region.
__global__ void k_build_wext(const float* __restrict__ Wres,
                             const float* __restrict__ Win,
                             short* __restrict__ Wext){
  int idx = blockIdx.x * 256 + threadIdx.x;       // 1024*1056 = 4224*256
  int r = idx / KE, k = idx % KE;
  float v = 0.0f;
  if (k < 1024)      v = Wres[(size_t)r * 1024 + k];
  else if (k < 1032) v = Win[r * 8 + (k - 1024)];
  Wext[idx] = (short)f2bf(v);
}

// ---- prep: zero the state region [0,1024) of each chunk's initial-read row ----
__global__ void k_zero_init(short* __restrict__ base, size_t rowstride){
  int idx = blockIdx.x * 256 + threadIdx.x;   // 2048 rows x 512 dwords
  int c = idx >> 9, d = idx & 511;
  ((unsigned*)(base + (size_t)c * rowstride))[d] = 0u;
}

// ---- prep: x-slot of each chunk's initial row, zero flags ----
__global__ void k_init_x(const float* __restrict__ in, short* __restrict__ x0,
                         size_t rowstride, unsigned* __restrict__ cnt){
  int c = blockIdx.x * 256 + threadIdx.x;
  if (c < NGRP * 16) cnt[c] = 0u;             // 32 groups x 8 flags (16-dw stride)
  if (c < CCH){
    int t0 = c * LCH - WARM;
    uint4 xv = {0,0,0,0};
    if (t0 >= 0){
      const float4 A4 = *(const float4*)(in + (size_t)t0 * 8);
      const float4 B4 = *(const float4*)(in + (size_t)t0 * 8 + 4);
      xv.x = f2bf(A4.x) | ((unsigned)f2bf(A4.y) << 16);
      xv.y = f2bf(A4.z) | ((unsigned)f2bf(A4.w) << 16);
      xv.z = f2bf(B4.x) | ((unsigned)f2bf(B4.y) << 16);
      xv.w = f2bf(B4.z) | ((unsigned)f2bf(B4.w) << 16);
    }
    *(uint4*)(x0 + (size_t)c * rowstride) = xv;
  }
}

// ---- output rows 1024..1031 = inputs^T (exact fp32 copy) ----
__global__ void k_xrows(const float* __restrict__ in, float* __restrict__ out){
  int t = blockIdx.x * 256 + threadIdx.x;
  const float4 a = *(const float4*)(in + (size_t)t * 8);
  const float4 b = *(const float4*)(in + (size_t)t * 8 + 4);
  out[(size_t)(R_DIM + 0) * T_LEN + t] = a.x;
  out[(size_t)(R_DIM + 1) * T_LEN + t] = a.y;
  out[(size_t)(R_DIM + 2) * T_LEN + t] = a.z;
  out[(size_t)(R_DIM + 3) * T_LEN + t] = a.w;
  out[(size_t)(R_DIM + 4) * T_LEN + t] = b.x;
  out[(size_t)(R_DIM + 5) * T_LEN + t] = b.y;
  out[(size_t)(R_DIM + 6) * T_LEN + t] = b.z;
  out[(size_t)(R_DIM + 7) * T_LEN + t] = b.w;
}

// ---- hist[t][r] (bf16) -> out[r][t] (f32), tiled transpose ----
__global__ void k_transpose(const short* __restrict__ hist, float* __restrict__ out){
  __shared__ float tile[64][65];
  const int t0 = blockIdx.x * 64;
  const int r0 = blockIdx.y * 64;
  for (int it = 0; it < 2; ++it){
    int id = it * 256 + threadIdx.x;     // 512 chunks of 8 bf16
    int tr = id >> 3;
    int c8 = (id & 7) * 8;
    short8 v = *(const short8*)(hist + (size_t)(t0 + tr) * KE + r0 + c8);
    #pragma unroll
    for (int j = 0; j < 8; ++j){
      unsigned u = ((unsigned)(unsigned short)v[j]) << 16;
      tile[tr][c8 + j] = __builtin_bit_cast(float, u);
    }
  }
  __syncthreads();
  #pragma unroll
  for (int p = 0; p < 16; ++p){
    int rr = (threadIdx.x >> 6) + p * 4;
    int tc = threadIdx.x & 63;
    out[(size_t)(r0 + rr) * T_LEN + t0 + tc] = tile[tc][rr];
  }
}

// ---- main stepped kernel: 256 WGs x 512 thr (1 WG/CU); WG = 128 rows x 64 cols.
// A in VGPRs (136/wave, K split across wave pairs) -> REQUIRES 2 waves/SIMD
// (launch_bounds(512,2), <=256 unified regs). 64 cols amortizes the fixed
// per-step latency chain (poll RT + stage RT + drain RT) over 2x the work,
// halving step count to 48. All cross-WG data via sc0/sc1 coherence-point
// accesses; fence-free flag sync. Warmup ping-pongs in hist rows 0/1 per chunk.
template<bool HIST>
__global__ __launch_bounds__(512, 2)
void k_esn(const float* __restrict__ inputs, const short* __restrict__ Wext,
           short* __restrict__ S0, short* __restrict__ S1,
           short* __restrict__ hist, unsigned* __restrict__ cnt,
           float* __restrict__ out)
{
  extern __shared__ __align__(16) char lds[];   // LDSB: 64 cols x 2048B, XOR-swizzled
  const int tid  = threadIdx.x;
  const int g    = blockIdx.x >> 3;
  const int rwg  = blockIdx.x & 7;
  const int wv   = tid >> 6;                  // 0..7
  const int lane = tid & 63;
  const int l15  = lane & 15, l4 = lane >> 4;
  const int hi   = wv & 1;                    // K-half of this wave
  const int rbase = rwg * 128 + (wv >> 1) * 32;
  const int colbase = g * WGC;
  unsigned* gflags = cnt + g * 16;            // 8 dword flags in one 64B line

  // read-row for step k (state s_{k-1}); warmup parity: read slot (k+1)&1.
  auto browf = [&](int col, int k) -> const short* {
    if (HIST){
      size_t row = (k <= WARM) ? ((size_t)col * LCH + ((k + 1) & 1))
                               : ((size_t)col * LCH + (size_t)(k - WARM) - 1);
      return hist + row * KE;
    }
    return ((k & 1) ? S1 : S0) + (size_t)col * KE;
  };
  // write-row for step k's output (consumed by step k+1)
  auto wrowf = [&](int col, int k) -> short* {
    if (HIST){
      size_t row = (k < WARM) ? ((size_t)col * LCH + (k & 1))
                              : ((size_t)col * LCH + (size_t)(k - WARM));
      return hist + row * KE;
    }
    return ((k & 1) ? S0 : S1) + (size_t)col * KE;
  };

  // ---- loop-invariant A fragments in registers ----
  // hi=0: kk 0..16 (17 frags); hi=1: kk 17..32 (16 frags; kk32 = global-B tail)
  const int NA = hi ? 16 : 17;
  const int KB = hi ? 17 : 0;
  const int NL = hi ? 15 : 17;   // frags consumed from LDS
  short8 a0[17], a1[17];
  {
    const short* abase = Wext + (size_t)(rbase + l15) * KE + l4 * 8;
    #pragma unroll
    for (int i = 0; i < 17; ++i){
      if (i < NA){
        const short* ap = abase + (KB + i) * 32;
        a0[i] = *(const short8*)ap;
        a1[i] = *(const short8*)(ap + (size_t)16 * KE);
      }
    }
  }

  // staging geometry: 16 threads per col, 256B contiguous per thread-set,
  // 8 passes of 256B per col; each thread handles cols {scol, scol+32}.
  const int scol = tid >> 4;                  // 0..31
  const int skb0 = (tid & 15) << 4;
  const int sswz = (scol & 7) << 4;           // same for scol+32 (mod-8 equal)
  // B-frag read geometry
  const int colb0 = l15 * 2048;
  const int bswz  = (l15 & 7) << 4;
  const int l4b   = l4 * 16;
  // exchange geometry: conflict-free octets (bits[6:4] = (lane&7)^(lane>>3))
  const int xsw = (lane * 16) ^ ((lane >> 3) << 4);

  for (int k = 0; k < STEPS; ++k){
    // ---- wait for all 8 producers of this group (fence-free flag poll) ----
    if (k > 0){
      if (wv == 0){
        const unsigned* fp = gflags + (lane & 7);
        int guard = 0;
        for (;;){
          unsigned v;
          asm volatile("global_load_dword %0, %1, off sc0 sc1\n\t"
                       "s_waitcnt vmcnt(0)"
                       : "=v"(v) : "v"(fp) : "memory");
          if (!__any((int)(v < (unsigned)k))) break;
          __builtin_amdgcn_s_sleep(1);
          if (++guard > 1000000) break;      // failsafe: degrade, don't hang
        }
      }
      __syncthreads();                        // A
    }

    // ---- K-ext tail B loads first (latency overlaps staging) ----
    unsigned long long tl[8];
    if (hi){
      #pragma unroll
      for (int ct = 0; ct < 4; ++ct){
        const unsigned long long* tp =
          (const unsigned long long*)(browf(colbase + ct * 16 + l15, k) + 1024 + l4 * 8);
        tl[ct * 2]     = __hip_atomic_load(tp,     __ATOMIC_RELAXED, __HIP_MEMORY_SCOPE_AGENT);
        tl[ct * 2 + 1] = __hip_atomic_load(tp + 1, __ATOMIC_RELAXED, __HIP_MEMORY_SCOPE_AGENT);
      }
    }

    // ---- stage B (k<1024, 64 cols = 128KB) into LDS via sc0/sc1 loads ----
    {
      const char* sp0 = (const char*)browf(colbase + scol, k) + skb0;
      const char* sp1 = (const char*)browf(colbase + scol + 32, k) + skb0;
      u32x4 r0,r1,r2,r3,r4,r5,r6,r7,r8,r9,r10,r11,r12,r13,r14,r15;
      asm volatile(
        "global_load_dwordx4 %0, %16, off sc0 sc1\n\t"
        "global_load_dwordx4 %1, %16, off offset:256 sc0 sc1\n\t"
        "global_load_dwordx4 %2, %16, off offset:512 sc0 sc1\n\t"
        "global_load_dwordx4 %3, %16, off offset:768 sc0 sc1\n\t"
        "global_load_dwordx4 %4, %16, off offset:1024 sc0 sc1\n\t"
        "global_load_dwordx4 %5, %16, off offset:1280 sc0 sc1\n\t"
        "global_load_dwordx4 %6, %16, off offset:1536 sc0 sc1\n\t"
        "global_load_dwordx4 %7, %16, off offset:1792 sc0 sc1\n\t"
        "global_load_dwordx4 %8, %17, off sc0 sc1\n\t"
        "global_load_dwordx4 %9, %17, off offset:256 sc0 sc1\n\t"
        "global_load_dwordx4 %10, %17, off offset:512 sc0 sc1\n\t"
        "global_load_dwordx4 %11, %17, off offset:768 sc0 sc1\n\t"
        "global_load_dwordx4 %12, %17, off offset:1024 sc0 sc1\n\t"
        "global_load_dwordx4 %13, %17, off offset:1280 sc0 sc1\n\t"
        "global_load_dwordx4 %14, %17, off offset:1536 sc0 sc1\n\t"
        "global_load_dwordx4 %15, %17, off offset:1792 sc0 sc1\n\t"
        "s_waitcnt vmcnt(0)"
        : "=&v"(r0),"=&v"(r1),"=&v"(r2),"=&v"(r3),
          "=&v"(r4),"=&v"(r5),"=&v"(r6),"=&v"(r7),
          "=&v"(r8),"=&v"(r9),"=&v"(r10),"=&v"(r11),
          "=&v"(r12),"=&v"(r13),"=&v"(r14),"=&v"(r15)
        : "v"(sp0), "v"(sp1) : "memory");
      char* dst0 = &lds[scol * 2048];
      char* dst1 = &lds[(scol + 32) * 2048];
      *(u32x4*)(dst0 + ((skb0 +    0) ^ sswz)) = r0;
      *(u32x4*)(dst0 + ((skb0 +  256) ^ sswz)) = r1;
      *(u32x4*)(dst0 + ((skb0 +  512) ^ sswz)) = r2;
      *(u32x4*)(dst0 + ((skb0 +  768) ^ sswz)) = r3;
      *(u32x4*)(dst0 + ((skb0 + 1024) ^ sswz)) = r4;
      *(u32x4*)(dst0 + ((skb0 + 1280) ^ sswz)) = r5;
      *(u32x4*)(dst0 + ((skb0 + 1536) ^ sswz)) = r6;
      *(u32x4*)(dst0 + ((skb0 + 1792) ^ sswz)) = r7;
      *(u32x4*)(dst1 + ((skb0 +    0) ^ sswz)) = r8;
      *(u32x4*)(dst1 + ((skb0 +  256) ^ sswz)) = r9;
      *(u32x4*)(dst1 + ((skb0 +  512) ^ sswz)) = r10;
      *(u32x4*)(dst1 + ((skb0 +  768) ^ sswz)) = r11;
      *(u32x4*)(dst1 + ((skb0 + 1024) ^ sswz)) = r12;
      *(u32x4*)(dst1 + ((skb0 + 1280) ^ sswz)) = r13;
      *(u32x4*)(dst1 + ((skb0 + 1536) ^ sswz)) = r14;
      *(u32x4*)(dst1 + ((skb0 + 1792) ^ sswz)) = r15;
    }
    __syncthreads();                          // B

    // ---- MFMA K-loop (A from regs, B from LDS, 4 col-tiles) ----
    f32x4 acc0[4], acc1[4];
    #pragma unroll
    for (int ct = 0; ct < 4; ++ct){ acc0[ct] = f32x4{0,0,0,0}; acc1[ct] = f32x4{0,0,0,0}; }
    #pragma unroll
    for (int i = 0; i < 17; ++i){
      if (i < NL){
        int kb = (KB + i) * 64 + l4b;
        #pragma unroll
        for (int ct = 0; ct < 4; ++ct){
          const short8 b = *(const short8*)(&lds[colb0 + ct * 32768 + (kb ^ bswz)]);
          acc0[ct] = __builtin_amdgcn_mfma_f32_16x16x32_bf16(a0[i], b, acc0[ct], 0, 0, 0);
          acc1[ct] = __builtin_amdgcn_mfma_f32_16x16x32_bf16(a1[i], b, acc1[ct], 0, 0, 0);
        }
      }
    }
    if (hi){   // kk=32 tail: A index 15, B from registers (pad nulled by Wext zeros)
      #pragma unroll
      for (int ct = 0; ct < 4; ++ct){
        u32x4 v; v.x = (unsigned)tl[ct*2];     v.y = (unsigned)(tl[ct*2] >> 32);
                 v.z = (unsigned)tl[ct*2 + 1]; v.w = (unsigned)(tl[ct*2 + 1] >> 32);
        const short8 b = __builtin_bit_cast(short8, v);
        acc0[ct] = __builtin_amdgcn_mfma_f32_16x16x32_bf16(a0[15], b, acc0[ct], 0, 0, 0);
        acc1[ct] = __builtin_amdgcn_mfma_f32_16x16x32_bf16(a1[15], b, acc1[ct], 0, 0, 0);
      }
    }

    // ---- cross-pair K-reduction via LDS (reuse B region after barrier) ----
    __syncthreads();                          // C
    #pragma unroll
    for (int ct = 0; ct < 4; ++ct)
      *(f32x4*)(&lds[ct * 8192 + wv * 1024 + xsw]) = hi ? acc0[ct] : acc1[ct];
    __syncthreads();                          // D
    {
      const int rowb = rbase + hi * 16 + l4 * 4;
      #pragma unroll
      for (int ct = 0; ct < 4; ++ct){
        f32x4 p = *(const f32x4*)(&lds[ct * 8192 + (wv ^ 1) * 1024 + xsw]);
        f32x4 z = (hi ? acc1[ct] : acc0[ct]) + p;
        float s0 = fast_tanh(z[0]), s1 = fast_tanh(z[1]);
        float s2 = fast_tanh(z[2]), s3 = fast_tanh(z[3]);
        unsigned long long pk = (unsigned long long)f2bf(s0)
          | ((unsigned long long)f2bf(s1) << 16)
          | ((unsigned long long)f2bf(s2) << 32)
          | ((unsigned long long)f2bf(s3) << 48);
        int col = colbase + ct * 16 + l15;
        short* wp = wrowf(col, k) + rowb;
        asm volatile("global_store_dwordx2 %0, %1, off sc0 sc1"
                     :: "v"(wp), "v"(pk) : "memory");
        if (!HIST && k >= WARM){
          int tk = col * LCH + k - WARM;
          float* op = out + (size_t)rowb * T_LEN + tk;
          op[0] = s0; op[(size_t)T_LEN] = s1;
          op[(size_t)2 * T_LEN] = s2; op[(size_t)3 * T_LEN] = s3;
        }
      }
    }

    // ---- x for next step (one WG per group) ----
    if (rwg == 0 && tid < WGC && (k + 1) < STEPS){
      int col = colbase + tid;
      short* xr = wrowf(col, k) + 1024;
      int tn = col * LCH + (k + 1) - WARM;
      u32x4 xv = {0,0,0,0};
      if (tn >= 0){
        const float4 A4 = *(const float4*)(inputs + (size_t)tn * 8);
        const float4 B4 = *(const float4*)(inputs + (size_t)tn * 8 + 4);
        xv.x = f2bf(A4.x) | ((unsigned)f2bf(A4.y) << 16);
        xv.y = f2bf(A4.z) | ((unsigned)f2bf(A4.w) << 16);
        xv.z = f2bf(B4.x) | ((unsigned)f2bf(B4.y) << 16);
        xv.w = f2bf(B4.z) | ((unsigned)f2bf(B4.w) << 16);
      }
      asm volatile("global_store_dwordx4 %0, %1, off sc0 sc1"
                   :: "v"(xr), "v"(xv) : "memory");
    }

    // ---- drain own stores to coherence point, then signal via flag ----
    asm volatile("s_waitcnt vmcnt(0)" ::: "memory");
    __syncthreads();                          // E (all waves drained)
    if (tid == 0 && (k + 1) < STEPS){
      unsigned* fw = gflags + rwg;
      unsigned fv = (unsigned)(k + 1);
      asm volatile("global_store_dword %0, %1, off sc0 sc1"
                   :: "v"(fw), "v"(fv) : "memory");
    }
  }
}

extern "C" void kernel_launch(void* const* d_in, const int* in_sizes, int n_in,
                              void* d_out, int out_size, void* d_ws, size_t ws_size,
                              hipStream_t stream)
{
  (void)in_sizes; (void)n_in; (void)out_size;
  const float* inputs = (const float*)d_in[0];
  const float* Win    = (const float*)d_in[1];
  const float* Wres   = (const float*)d_in[2];
  float* out = (float*)d_out;
  char* ws = (char*)d_ws;

  short*    Wext = (short*)(ws);                       // 2,162,688 B
  unsigned* cnt  = (unsigned*)(ws + 2162688);          // 32 groups x 64B
  char*     data = ws + 2166784;
  short*    hist = (short*)data;                       // 65536*1056*2 = 138,412,032 B
  short*    S0   = (short*)data;                       // !HIST: 2048*1056*2 B
  short*    S1   = (short*)(data + 4325376);
  const bool hist_ok = ws_size >= (2166784ull + 138412032ull);

  hipLaunchKernelGGL(k_build_wext, dim3(4224), dim3(256), 0, stream, Wres, Win, Wext);
  hipLaunchKernelGGL(k_xrows,      dim3(256),  dim3(256), 0, stream, inputs, out);
  if (hist_ok){
    // zero state region of each chunk's warmup slot (+1 row), x into it, flags=0
    hipLaunchKernelGGL(k_zero_init, dim3(4096), dim3(256), 0, stream,
                       hist + KE, (size_t)LCH * KE);
    hipLaunchKernelGGL(k_init_x,    dim3(8),    dim3(256), 0, stream,
                       inputs, hist + KE + 1024, (size_t)LCH * KE, cnt);
    hipLaunchKernelGGL((k_esn<true>),  dim3(RWG * NGRP), dim3(512), LDSB, stream,
                       inputs, Wext, S0, S1, hist, cnt, out);
    hipLaunchKernelGGL(k_transpose, dim3(1024, 16), dim3(256), 0, stream, hist, out);
  } else {
    hipLaunchKernelGGL(k_zero_init, dim3(4096), dim3(256), 0, stream,
                       S0, (size_t)KE);
    hipLaunchKernelGGL(k_init_x,    dim3(8),    dim3(256), 0, stream,
                       inputs, S0 + 1024, (size_t)KE, cnt);
    hipLaunchKernelGGL((k_esn<false>), dim3(RWG * NGRP), dim3(512), LDSB, stream,
                       inputs, Wext, S0, S1, hist, cnt, out);
  }
}

// Round 7
// 549.103 us; speedup vs baseline: 1.9656x; 1.2331x over previous
//
#include <hip/hip_runtime.h>
#include <cstdint>

typedef __attribute__((ext_vector_type(8))) short short8;
typedef __attribute__((ext_vector_type(4))) float f32x4;
typedef __attribute__((ext_vector_type(4))) unsigned u32x4;

#define R_DIM 1024
#define KE    1056      // 1024 state + 8 x + 24 zero pad
#define T_LEN 65536
#define CCH   1024      // chunks (columns of the batched recurrence)
#define LCH   64        // real steps per chunk
#define WARM  16        // warmup steps (absmax flat 64->32->24->16 => at bf16 floor)
#define STEPS (WARM + LCH)   // 80
#define NGRP  32        // independent groups, 32 cols each
#define WGC   32        // cols per WG (= per group)
#define RWG   8         // row-WGs per group (128 rows each)

static __device__ __forceinline__ unsigned short f2bf(float f){
  unsigned u = __builtin_bit_cast(unsigned, f);
  u += 0x7fffu + ((u >> 16) & 1u);
  return (unsigned short)(u >> 16);
}
static __device__ __forceinline__ float fast_tanh(float x){
  float e = __expf(2.0f * x);          // inf/0 saturate correctly to +/-1
  return 1.0f - 2.0f / (e + 1.0f);
}

// ---- prep: W_ext = [W_res | W_in | 0] in bf16, row-major [1024][1056] ----
// zeros at k>=1032 are LOAD-BEARING: they null garbage in B pad region.
__global__ void k_build_wext(const float* __restrict__ Wres,
                             const float* __restrict__ Win,
                             short* __restrict__ Wext){
  int idx = blockIdx.x * 256 + threadIdx.x;       // 1024*1056 = 4224*256
  int r = idx / KE, k = idx % KE;
  float v = 0.0f;
  if (k < 1024)      v = Wres[(size_t)r * 1024 + k];
  else if (k < 1032) v = Win[r * 8 + (k - 1024)];
  Wext[idx] = (short)f2bf(v);
}

// ---- prep: zero the state region [0,1024) of each chunk's initial-read row ----
__global__ void k_zero_init(short* __restrict__ base, size_t rowstride){
  int idx = blockIdx.x * 256 + threadIdx.x;   // 1024 rows x 512 dwords = 2048 blocks
  int c = idx >> 9, d = idx & 511;
  ((unsigned*)(base + (size_t)c * rowstride))[d] = 0u;
}

// ---- prep: x-slot of each chunk's initial row, zero flags ----
__global__ void k_init_x(const float* __restrict__ in, short* __restrict__ x0,
                         size_t rowstride, unsigned* __restrict__ cnt){
  int c = blockIdx.x * 256 + threadIdx.x;
  if (c < NGRP * 16) cnt[c] = 0u;             // 32 groups x 8 flags (16-dw stride)
  if (c < CCH){
    int t0 = c * LCH - WARM;
    uint4 xv = {0,0,0,0};
    if (t0 >= 0){
      const float4 A4 = *(const float4*)(in + (size_t)t0 * 8);
      const float4 B4 = *(const float4*)(in + (size_t)t0 * 8 + 4);
      xv.x = f2bf(A4.x) | ((unsigned)f2bf(A4.y) << 16);
      xv.y = f2bf(A4.z) | ((unsigned)f2bf(A4.w) << 16);
      xv.z = f2bf(B4.x) | ((unsigned)f2bf(B4.y) << 16);
      xv.w = f2bf(B4.z) | ((unsigned)f2bf(B4.w) << 16);
    }
    *(uint4*)(x0 + (size_t)c * rowstride) = xv;
  }
}

// ---- output rows 1024..1031 = inputs^T (exact fp32 copy) ----
__global__ void k_xrows(const float* __restrict__ in, float* __restrict__ out){
  int t = blockIdx.x * 256 + threadIdx.x;
  const float4 a = *(const float4*)(in + (size_t)t * 8);
  const float4 b = *(const float4*)(in + (size_t)t * 8 + 4);
  out[(size_t)(R_DIM + 0) * T_LEN + t] = a.x;
  out[(size_t)(R_DIM + 1) * T_LEN + t] = a.y;
  out[(size_t)(R_DIM + 2) * T_LEN + t] = a.z;
  out[(size_t)(R_DIM + 3) * T_LEN + t] = a.w;
  out[(size_t)(R_DIM + 4) * T_LEN + t] = b.x;
  out[(size_t)(R_DIM + 5) * T_LEN + t] = b.y;
  out[(size_t)(R_DIM + 6) * T_LEN + t] = b.z;
  out[(size_t)(R_DIM + 7) * T_LEN + t] = b.w;
}

// ---- hist[t][r] (bf16) -> out[r][t] (f32), tiled transpose ----
__global__ void k_transpose(const short* __restrict__ hist, float* __restrict__ out){
  __shared__ float tile[64][65];
  const int t0 = blockIdx.x * 64;
  const int r0 = blockIdx.y * 64;
  for (int it = 0; it < 2; ++it){
    int id = it * 256 + threadIdx.x;     // 512 chunks of 8 bf16
    int tr = id >> 3;
    int c8 = (id & 7) * 8;
    short8 v = *(const short8*)(hist + (size_t)(t0 + tr) * KE + r0 + c8);
    #pragma unroll
    for (int j = 0; j < 8; ++j){
      unsigned u = ((unsigned)(unsigned short)v[j]) << 16;
      tile[tr][c8 + j] = __builtin_bit_cast(float, u);
    }
  }
  __syncthreads();
  #pragma unroll
  for (int p = 0; p < 16; ++p){
    int rr = (threadIdx.x >> 6) + p * 4;
    int tc = threadIdx.x & 63;
    out[(size_t)(r0 + rr) * T_LEN + t0 + tc] = tile[tc][rr];
  }
}

// ---- main stepped kernel: 256 WGs x 512 thr (1 WG/CU); WG = 128 rows x 32 cols.
// A in VGPRs (K split across wave pairs), LB(512,1) = the proven no-spill regime.
// bid = rwg*32 + g: under round-robin dispatch all 8 WGs of a group share one
// XCD (perf hint only). Staging loads are PLAIN (cached L2/L3) for k>WARM+2 —
// safe because those hist rows are write-once and flag-gated (first touch
// always fills from L3, which the producer's sc0/sc1 store already reached);
// warmup ping-pong rows (rewritten) keep the sc0/sc1 path. State stores and
// flags remain sc0/sc1 (no XCD assumption for correctness).
template<bool HIST>
__global__ __launch_bounds__(512, 1)
void k_esn(const float* __restrict__ inputs, const short* __restrict__ Wext,
           short* __restrict__ S0, short* __restrict__ S1,
           short* __restrict__ hist, unsigned* __restrict__ cnt,
           float* __restrict__ out)
{
  __shared__ __align__(16) char lds[65536];   // 32 cols x 2048B, XOR-swizzled
  const int tid  = threadIdx.x;
  const int g    = blockIdx.x & (NGRP - 1);
  const int rwg  = blockIdx.x >> 5;           // bid=rwg*32+g -> group on one XCD
  const int wv   = tid >> 6;                  // 0..7
  const int lane = tid & 63;
  const int l15  = lane & 15, l4 = lane >> 4;
  const int hi   = wv & 1;                    // K-half of this wave
  const int rbase = rwg * 128 + (wv >> 1) * 32;
  const int colbase = g * WGC;
  unsigned* gflags = cnt + g * 16;            // 8 dword flags in one 64B line

  // read-row for step k (state s_{k-1}); warmup parity: read slot (k+1)&1.
  auto browf = [&](int col, int k) -> const short* {
    if (HIST){
      size_t row = (k <= WARM) ? ((size_t)col * LCH + ((k + 1) & 1))
                               : ((size_t)col * LCH + (size_t)(k - WARM) - 1);
      return hist + row * KE;
    }
    return ((k & 1) ? S1 : S0) + (size_t)col * KE;
  };
  // write-row for step k's output (consumed by step k+1)
  auto wrowf = [&](int col, int k) -> short* {
    if (HIST){
      size_t row = (k < WARM) ? ((size_t)col * LCH + (k & 1))
                              : ((size_t)col * LCH + (size_t)(k - WARM));
      return hist + row * KE;
    }
    return ((k & 1) ? S0 : S1) + (size_t)col * KE;
  };

  // ---- loop-invariant A fragments in registers ----
  // hi=0: kk 0..16 (17 frags); hi=1: kk 17..32 (16 frags; kk32 = global-B tail)
  const int NA = hi ? 16 : 17;
  const int KB = hi ? 17 : 0;
  const int NL = hi ? 15 : 17;   // frags consumed from LDS
  short8 a0[17], a1[17];
  {
    const short* abase = Wext + (size_t)(rbase + l15) * KE + l4 * 8;
    #pragma unroll
    for (int i = 0; i < 17; ++i){
      if (i < NA){
        const short* ap = abase + (KB + i) * 32;
        a0[i] = *(const short8*)ap;
        a1[i] = *(const short8*)(ap + (size_t)16 * KE);
      }
    }
  }

  // staging geometry: thread owns col (tid>>4), 8 chunks of 16B spaced 256B
  const int scol = tid >> 4;
  const int skb0 = (tid & 15) << 4;
  const int sswz = (scol & 7) << 4;
  // B-frag read geometry
  const int colb0 = l15 * 2048;
  const int bswz  = (l15 & 7) << 4;
  const int l4b   = l4 * 16;
  // exchange geometry: conflict-free octets (bits[6:4] = (lane&7)^(lane>>3))
  const int xsw = (lane * 16) ^ ((lane >> 3) << 4);

  for (int k = 0; k < STEPS; ++k){
    // ---- wait for all 8 producers of this group (fence-free flag poll) ----
    if (k > 0){
      if (wv == 0){
        const unsigned* fp = gflags + (lane & 7);
        int guard = 0;
        for (;;){
          unsigned v;
          asm volatile("global_load_dword %0, %1, off sc0 sc1\n\t"
                       "s_waitcnt vmcnt(0)"
                       : "=v"(v) : "v"(fp) : "memory");
          if (!__any((int)(v < (unsigned)k))) break;
          __builtin_amdgcn_s_sleep(1);
          if (++guard > 1000000) break;      // failsafe: degrade, don't hang
        }
      }
      __syncthreads();                        // A
    }

    // ---- K-ext tail B loads first (latency overlaps staging) ----
    unsigned long long t00=0, t01=0, t10=0, t11=0;
    if (hi){
      const unsigned long long* tp0 =
        (const unsigned long long*)(browf(colbase + l15, k) + 1024 + l4 * 8);
      const unsigned long long* tp1 =
        (const unsigned long long*)(browf(colbase + 16 + l15, k) + 1024 + l4 * 8);
      t00 = __hip_atomic_load(tp0,     __ATOMIC_RELAXED, __HIP_MEMORY_SCOPE_AGENT);
      t01 = __hip_atomic_load(tp0 + 1, __ATOMIC_RELAXED, __HIP_MEMORY_SCOPE_AGENT);
      t10 = __hip_atomic_load(tp1,     __ATOMIC_RELAXED, __HIP_MEMORY_SCOPE_AGENT);
      t11 = __hip_atomic_load(tp1 + 1, __ATOMIC_RELAXED, __HIP_MEMORY_SCOPE_AGENT);
    }

    // ---- stage B (k<1024) into LDS ----
    // k<=WARM+2: sc0/sc1 (rows are rewritten ping-pong slots);
    // k> WARM+2: PLAIN cached loads (rows write-once + flag-gated => fresh).
    {
      const short* srow = browf(colbase + scol, k);
      const char* sp = (const char*)srow + skb0;
      u32x4 r0,r1,r2,r3,r4,r5,r6,r7;
      if (k <= WARM + 2){
        asm volatile(
          "global_load_dwordx4 %0, %8, off sc0 sc1\n\t"
          "global_load_dwordx4 %1, %8, off offset:256 sc0 sc1\n\t"
          "global_load_dwordx4 %2, %8, off offset:512 sc0 sc1\n\t"
          "global_load_dwordx4 %3, %8, off offset:768 sc0 sc1\n\t"
          "global_load_dwordx4 %4, %8, off offset:1024 sc0 sc1\n\t"
          "global_load_dwordx4 %5, %8, off offset:1280 sc0 sc1\n\t"
          "global_load_dwordx4 %6, %8, off offset:1536 sc0 sc1\n\t"
          "global_load_dwordx4 %7, %8, off offset:1792 sc0 sc1\n\t"
          "s_waitcnt vmcnt(0)"
          : "=&v"(r0),"=&v"(r1),"=&v"(r2),"=&v"(r3),
            "=&v"(r4),"=&v"(r5),"=&v"(r6),"=&v"(r7)
          : "v"(sp) : "memory");
      } else {
        asm volatile(
          "global_load_dwordx4 %0, %8, off\n\t"
          "global_load_dwordx4 %1, %8, off offset:256\n\t"
          "global_load_dwordx4 %2, %8, off offset:512\n\t"
          "global_load_dwordx4 %3, %8, off offset:768\n\t"
          "global_load_dwordx4 %4, %8, off offset:1024\n\t"
          "global_load_dwordx4 %5, %8, off offset:1280\n\t"
          "global_load_dwordx4 %6, %8, off offset:1536\n\t"
          "global_load_dwordx4 %7, %8, off offset:1792\n\t"
          "s_waitcnt vmcnt(0)"
          : "=&v"(r0),"=&v"(r1),"=&v"(r2),"=&v"(r3),
            "=&v"(r4),"=&v"(r5),"=&v"(r6),"=&v"(r7)
          : "v"(sp) : "memory");
      }
      char* dst = &lds[scol * 2048];
      *(u32x4*)(dst + ((skb0 +    0) ^ sswz)) = r0;
      *(u32x4*)(dst + ((skb0 +  256) ^ sswz)) = r1;
      *(u32x4*)(dst + ((skb0 +  512) ^ sswz)) = r2;
      *(u32x4*)(dst + ((skb0 +  768) ^ sswz)) = r3;
      *(u32x4*)(dst + ((skb0 + 1024) ^ sswz)) = r4;
      *(u32x4*)(dst + ((skb0 + 1280) ^ sswz)) = r5;
      *(u32x4*)(dst + ((skb0 + 1536) ^ sswz)) = r6;
      *(u32x4*)(dst + ((skb0 + 1792) ^ sswz)) = r7;
    }
    __syncthreads();                          // B

    // ---- MFMA K-loop (A from regs, B from LDS) ----
    f32x4 acc00 = {0,0,0,0}, acc01 = {0,0,0,0}, acc10 = {0,0,0,0}, acc11 = {0,0,0,0};
    #pragma unroll
    for (int i = 0; i < 17; ++i){
      if (i < NL){
        int kb = (KB + i) * 64 + l4b;
        const short8 b0 = *(const short8*)(&lds[colb0 + ((kb) ^ bswz)]);
        const short8 b1 = *(const short8*)(&lds[colb0 + 32768 + ((kb) ^ bswz)]);
        acc00 = __builtin_amdgcn_mfma_f32_16x16x32_bf16(a0[i], b0, acc00, 0, 0, 0);
        acc01 = __builtin_amdgcn_mfma_f32_16x16x32_bf16(a0[i], b1, acc01, 0, 0, 0);
        acc10 = __builtin_amdgcn_mfma_f32_16x16x32_bf16(a1[i], b0, acc10, 0, 0, 0);
        acc11 = __builtin_amdgcn_mfma_f32_16x16x32_bf16(a1[i], b1, acc11, 0, 0, 0);
      }
    }
    if (hi){   // kk=32 tail: A index 15, B from registers (pad nulled by Wext zeros)
      u32x4 v0; v0.x=(unsigned)t00; v0.y=(unsigned)(t00>>32); v0.z=(unsigned)t01; v0.w=(unsigned)(t01>>32);
      u32x4 v1; v1.x=(unsigned)t10; v1.y=(unsigned)(t10>>32); v1.z=(unsigned)t11; v1.w=(unsigned)(t11>>32);
      const short8 b0 = __builtin_bit_cast(short8, v0);
      const short8 b1 = __builtin_bit_cast(short8, v1);
      acc00 = __builtin_amdgcn_mfma_f32_16x16x32_bf16(a0[15], b0, acc00, 0, 0, 0);
      acc01 = __builtin_amdgcn_mfma_f32_16x16x32_bf16(a0[15], b1, acc01, 0, 0, 0);
      acc10 = __builtin_amdgcn_mfma_f32_16x16x32_bf16(a1[15], b0, acc10, 0, 0, 0);
      acc11 = __builtin_amdgcn_mfma_f32_16x16x32_bf16(a1[15], b1, acc11, 0, 0, 0);
    }

    // ---- cross-pair K-reduction via LDS (reuse B region after barrier) ----
    __syncthreads();                          // C
    {
      *(f32x4*)(&lds[wv * 1024 + xsw])        = hi ? acc00 : acc10;
      *(f32x4*)(&lds[8192 + wv * 1024 + xsw]) = hi ? acc01 : acc11;
    }
    __syncthreads();                          // D
    {
      f32x4 p0 = *(const f32x4*)(&lds[(wv ^ 1) * 1024 + xsw]);
      f32x4 p1 = *(const f32x4*)(&lds[8192 + (wv ^ 1) * 1024 + xsw]);
      f32x4 f0 = (hi ? acc10 : acc00) + p0;   // own row-tile + partner's partial
      f32x4 f1 = (hi ? acc11 : acc01) + p1;
      const int rowb = rbase + hi * 16 + l4 * 4;
      #pragma unroll
      for (int ct = 0; ct < 2; ++ct){
        f32x4 z = ct ? f1 : f0;
        float s0 = fast_tanh(z[0]), s1 = fast_tanh(z[1]);
        float s2 = fast_tanh(z[2]), s3 = fast_tanh(z[3]);
        unsigned long long pk = (unsigned long long)f2bf(s0)
          | ((unsigned long long)f2bf(s1) << 16)
          | ((unsigned long long)f2bf(s2) << 32)
          | ((unsigned long long)f2bf(s3) << 48);
        int col = colbase + ct * 16 + l15;
        short* wp = wrowf(col, k) + rowb;
        asm volatile("global_store_dwordx2 %0, %1, off sc0 sc1"
                     :: "v"(wp), "v"(pk) : "memory");
        if (!HIST && k >= WARM){
          int tk = col * LCH + k - WARM;
          float* op = out + (size_t)rowb * T_LEN + tk;
          op[0] = s0; op[(size_t)T_LEN] = s1;
          op[(size_t)2 * T_LEN] = s2; op[(size_t)3 * T_LEN] = s3;
        }
      }
    }

    // ---- x for next step (one WG per group) ----
    if (rwg == 0 && tid < WGC && (k + 1) < STEPS){
      int col = colbase + tid;
      short* xr = wrowf(col, k) + 1024;
      int tn = col * LCH + (k + 1) - WARM;
      u32x4 xv = {0,0,0,0};
      if (tn >= 0){
        const float4 A4 = *(const float4*)(inputs + (size_t)tn * 8);
        const float4 B4 = *(const float4*)(inputs + (size_t)tn * 8 + 4);
        xv.x = f2bf(A4.x) | ((unsigned)f2bf(A4.y) << 16);
        xv.y = f2bf(A4.z) | ((unsigned)f2bf(A4.w) << 16);
        xv.z = f2bf(B4.x) | ((unsigned)f2bf(B4.y) << 16);
        xv.w = f2bf(B4.z) | ((unsigned)f2bf(B4.w) << 16);
      }
      asm volatile("global_store_dwordx4 %0, %1, off sc0 sc1"
                   :: "v"(xr), "v"(xv) : "memory");
    }

    // ---- drain own stores to coherence point, then signal via flag ----
    asm volatile("s_waitcnt vmcnt(0)" ::: "memory");
    __syncthreads();                          // E (all waves drained)
    if (tid == 0 && (k + 1) < STEPS){
      unsigned* fw = gflags + rwg;
      unsigned fv = (unsigned)(k + 1);
      asm volatile("global_store_dword %0, %1, off sc0 sc1"
                   :: "v"(fw), "v"(fv) : "memory");
    }
  }
}

extern "C" void kernel_launch(void* const* d_in, const int* in_sizes, int n_in,
                              void* d_out, int out_size, void* d_ws, size_t ws_size,
                              hipStream_t stream)
{
  (void)in_sizes; (void)n_in; (void)out_size;
  const float* inputs = (const float*)d_in[0];
  const float* Win    = (const float*)d_in[1];
  const float* Wres   = (const float*)d_in[2];
  float* out = (float*)d_out;
  char* ws = (char*)d_ws;

  short*    Wext = (short*)(ws);                       // 2,162,688 B
  unsigned* cnt  = (unsigned*)(ws + 2162688);          // 32 groups x 64B
  char*     data = ws + 2166784;
  short*    hist = (short*)data;                       // 65536*1056*2 = 138,412,032 B
  short*    S0   = (short*)data;                       // !HIST: 1024*1056*2 B
  short*    S1   = (short*)(data + 2162688);
  const bool hist_ok = ws_size >= (2166784ull + 138412032ull);

  hipLaunchKernelGGL(k_build_wext, dim3(4224), dim3(256), 0, stream, Wres, Win, Wext);
  hipLaunchKernelGGL(k_xrows,      dim3(256),  dim3(256), 0, stream, inputs, out);
  if (hist_ok){
    // zero state region of each chunk's warmup slot (+1 row), x into it, flags=0
    hipLaunchKernelGGL(k_zero_init, dim3(2048), dim3(256), 0, stream,
                       hist + KE, (size_t)LCH * KE);
    hipLaunchKernelGGL(k_init_x,    dim3(4),    dim3(256), 0, stream,
                       inputs, hist + KE + 1024, (size_t)LCH * KE, cnt);
    hipLaunchKernelGGL((k_esn<true>),  dim3(RWG * NGRP), dim3(512), 0, stream,
                       inputs, Wext, S0, S1, hist, cnt, out);
    hipLaunchKernelGGL(k_transpose, dim3(1024, 16), dim3(256), 0, stream, hist, out);
  } else {
    hipLaunchKernelGGL(k_zero_init, dim3(2048), dim3(256), 0, stream,
                       S0, (size_t)KE);
    hipLaunchKernelGGL(k_init_x,    dim3(4),    dim3(256), 0, stream,
                       inputs, S0 + 1024, (size_t)KE, cnt);
    hipLaunchKernelGGL((k_esn<false>), dim3(RWG * NGRP), dim3(512), 0, stream,
                       inputs, Wext, S0, S1, hist, cnt, out);
  }
}

// Round 8
// 538.330 us; speedup vs baseline: 2.0050x; 1.0200x over previous
//
#include <hip/hip_runtime.h>
#include <cstdint>

typedef __attribute__((ext_vector_type(8))) short short8;
typedef __attribute__((ext_vector_type(4))) float f32x4;
typedef __attribute__((ext_vector_type(4))) unsigned u32x4;

#define R_DIM 1024
#define KE    1056      // 1024 state + 8 x + 24 zero pad
#define T_LEN 65536
#define CCH   2048      // chunks
#define LCH   32        // real steps per chunk
#define WARM  16        // warmup steps
#define STEPS (WARM + LCH)   // 48
#define NGRP  32        // groups, 64 cols each
#define WGC   64        // cols per WG
#define RWG   8         // row-WGs per group (128 rows each)
#define LDSB  131072    // 2 halves x 32 cols x 2048B

static __device__ __forceinline__ unsigned short f2bf(float f){
  unsigned u = __builtin_bit_cast(unsigned, f);
  u += 0x7fffu + ((u >> 16) & 1u);
  return (unsigned short)(u >> 16);
}
static __device__ __forceinline__ float fast_tanh(float x){
  float e = __expf(2.0f * x);          // inf/0 saturate correctly to +/-1
  return 1.0f - 2.0f / (e + 1.0f);
}

// ---- prep: W_ext = [W_res | W_in | 0] in bf16, row-major [1024][1056] ----
__global__ void k_build_wext(const float* __restrict__ Wres,
                             const float* __restrict__ Win,
                             short* __restrict__ Wext){
  int idx = blockIdx.x * 256 + threadIdx.x;       // 1024*1056 = 4224*256
  int r = idx / KE, k = idx % KE;
  float v = 0.0f;
  if (k < 1024)      v = Wres[(size_t)r * 1024 + k];
  else if (k < 1032) v = Win[r * 8 + (k - 1024)];
  Wext[idx] = (short)f2bf(v);
}

// ---- prep: zero state region [0,1024) of each chunk's initial-read row ----
__global__ void k_zero_init(short* __restrict__ base, size_t rowstride){
  int idx = blockIdx.x * 256 + threadIdx.x;   // 2048 rows x 512 dwords
  int c = idx >> 9, d = idx & 511;
  ((unsigned*)(base + (size_t)c * rowstride))[d] = 0u;
}

// ---- prep: x-slot of each chunk's initial row, zero flags ----
__global__ void k_init_x(const float* __restrict__ in, short* __restrict__ x0,
                         size_t rowstride, unsigned* __restrict__ cnt){
  int c = blockIdx.x * 256 + threadIdx.x;
  if (c < NGRP * 16) cnt[c] = 0u;             // 32 groups x 8 flags (16-dw stride)
  if (c < CCH){
    int t0 = c * LCH - WARM;
    uint4 xv = {0,0,0,0};
    if (t0 >= 0){
      const float4 A4 = *(const float4*)(in + (size_t)t0 * 8);
      const float4 B4 = *(const float4*)(in + (size_t)t0 * 8 + 4);
      xv.x = f2bf(A4.x) | ((unsigned)f2bf(A4.y) << 16);
      xv.y = f2bf(A4.z) | ((unsigned)f2bf(A4.w) << 16);
      xv.z = f2bf(B4.x) | ((unsigned)f2bf(B4.y) << 16);
      xv.w = f2bf(B4.z) | ((unsigned)f2bf(B4.w) << 16);
    }
    *(uint4*)(x0 + (size_t)c * rowstride) = xv;
  }
}

// ---- output rows 1024..1031 = inputs^T (exact fp32 copy) ----
__global__ void k_xrows(const float* __restrict__ in, float* __restrict__ out){
  int t = blockIdx.x * 256 + threadIdx.x;
  const float4 a = *(const float4*)(in + (size_t)t * 8);
  const float4 b = *(const float4*)(in + (size_t)t * 8 + 4);
  out[(size_t)(R_DIM + 0) * T_LEN + t] = a.x;
  out[(size_t)(R_DIM + 1) * T_LEN + t] = a.y;
  out[(size_t)(R_DIM + 2) * T_LEN + t] = a.z;
  out[(size_t)(R_DIM + 3) * T_LEN + t] = a.w;
  out[(size_t)(R_DIM + 4) * T_LEN + t] = b.x;
  out[(size_t)(R_DIM + 5) * T_LEN + t] = b.y;
  out[(size_t)(R_DIM + 6) * T_LEN + t] = b.z;
  out[(size_t)(R_DIM + 7) * T_LEN + t] = b.w;
}

// ---- hist[t][r] (bf16) -> out[r][t] (f32), tiled transpose ----
__global__ void k_transpose(const short* __restrict__ hist, float* __restrict__ out){
  __shared__ float tile[64][65];
  const int t0 = blockIdx.x * 64;
  const int r0 = blockIdx.y * 64;
  for (int it = 0; it < 2; ++it){
    int id = it * 256 + threadIdx.x;     // 512 chunks of 8 bf16
    int tr = id >> 3;
    int c8 = (id & 7) * 8;
    short8 v = *(const short8*)(hist + (size_t)(t0 + tr) * KE + r0 + c8);
    #pragma unroll
    for (int j = 0; j < 8; ++j){
      unsigned u = ((unsigned)(unsigned short)v[j]) << 16;
      tile[tr][c8 + j] = __builtin_bit_cast(float, u);
    }
  }
  __syncthreads();
  #pragma unroll
  for (int p = 0; p < 16; ++p){
    int rr = (threadIdx.x >> 6) + p * 4;
    int tc = threadIdx.x & 63;
    out[(size_t)(r0 + rr) * T_LEN + t0 + tc] = tile[tc][rr];
  }
}

// ---- main: 256 WGs x 512 thr (1 WG/CU); WG = 128 rows x 64 cols, 2 halves.
// Per-half flags (value 2k+1 after H0 stores drain, 2k+2 after H1): each poll's
// target was signaled ~half a step earlier -> polls pre-satisfied; H0 store
// drain shares the vmcnt(0) of H1's staging loads (counted-wait: stores are
// oldest). A in VGPRs, K split across wave pairs; LB(512,1) (no-spill regime).
template<bool HIST>
__global__ __launch_bounds__(512, 1)
void k_esn(const float* __restrict__ inputs, const short* __restrict__ Wext,
           short* __restrict__ S0, short* __restrict__ S1,
           short* __restrict__ hist, unsigned* __restrict__ cnt,
           float* __restrict__ out)
{
  extern __shared__ __align__(16) char lds[];   // [hb*65536 + col*2048], XOR-swizzled
  const int tid  = threadIdx.x;
  const int g    = blockIdx.x & (NGRP - 1);
  const int rwg  = blockIdx.x >> 5;           // bid=rwg*32+g -> group on one XCD
  const int wv   = tid >> 6;                  // 0..7
  const int lane = tid & 63;
  const int l15  = lane & 15, l4 = lane >> 4;
  const int hi   = wv & 1;                    // K-half of this wave
  const int rbase = rwg * 128 + (wv >> 1) * 32;
  const int colbase = g * WGC;
  unsigned* gflags = cnt + g * 16;            // 8 dword flags in one 64B line

  auto browf = [&](int col, int k) -> const short* {
    if (HIST){
      size_t row = (k <= WARM) ? ((size_t)col * LCH + ((k + 1) & 1))
                               : ((size_t)col * LCH + (size_t)(k - WARM) - 1);
      return hist + row * KE;
    }
    return ((k & 1) ? S1 : S0) + (size_t)col * KE;
  };
  auto wrowf = [&](int col, int k) -> short* {
    if (HIST){
      size_t row = (k < WARM) ? ((size_t)col * LCH + (k & 1))
                              : ((size_t)col * LCH + (size_t)(k - WARM));
      return hist + row * KE;
    }
    return ((k & 1) ? S0 : S1) + (size_t)col * KE;
  };

  // ---- loop-invariant A fragments ----
  const int NA = hi ? 16 : 17;
  const int KB = hi ? 17 : 0;
  const int NL = hi ? 15 : 17;
  short8 a0[17], a1[17];
  {
    const short* abase = Wext + (size_t)(rbase + l15) * KE + l4 * 8;
    #pragma unroll
    for (int i = 0; i < 17; ++i){
      if (i < NA){
        const short* ap = abase + (KB + i) * 32;
        a0[i] = *(const short8*)ap;
        a1[i] = *(const short8*)(ap + (size_t)16 * KE);
      }
    }
  }

  const int scol = tid >> 4;                  // col within half (0..31)
  const int skb0 = (tid & 15) << 4;
  const int sswz = (scol & 7) << 4;
  const int colb0 = l15 * 2048;
  const int bswz  = (l15 & 7) << 4;
  const int l4b   = l4 * 16;
  const int xsw = (lane * 16) ^ ((lane >> 3) << 4);

  // poll helper (wv0 lanes 0..7 each watch one flag)
  auto poll = [&](unsigned target){
    if (wv == 0){
      const unsigned* fp = gflags + (lane & 7);
      int guard = 0;
      for (;;){
        unsigned v;
        asm volatile("global_load_dword %0, %1, off sc0 sc1\n\t"
                     "s_waitcnt vmcnt(0)"
                     : "=v"(v) : "v"(fp) : "memory");
        if (!__any((int)(v < target))) break;
        __builtin_amdgcn_s_sleep(1);
        if (++guard > 1000000) break;
      }
    }
    __syncthreads();
  };

  for (int k = 0; k < STEPS; ++k){
    const bool coh = (!HIST) || (k <= WARM + 2);
    #pragma unroll
    for (int hb = 0; hb < 2; ++hb){
      // ---- wait for producers of this half's inputs ----
      if (k > 0) poll((unsigned)(2 * k - 1 + hb));

      // ---- K-ext tail B loads (overlap staging) ----
      unsigned long long t00=0, t01=0, t10=0, t11=0;
      if (hi){
        const unsigned long long* tp0 =
          (const unsigned long long*)(browf(colbase + hb * 32 + l15, k) + 1024 + l4 * 8);
        const unsigned long long* tp1 =
          (const unsigned long long*)(browf(colbase + hb * 32 + 16 + l15, k) + 1024 + l4 * 8);
        t00 = __hip_atomic_load(tp0,     __ATOMIC_RELAXED, __HIP_MEMORY_SCOPE_AGENT);
        t01 = __hip_atomic_load(tp0 + 1, __ATOMIC_RELAXED, __HIP_MEMORY_SCOPE_AGENT);
        t10 = __hip_atomic_load(tp1,     __ATOMIC_RELAXED, __HIP_MEMORY_SCOPE_AGENT);
        t11 = __hip_atomic_load(tp1 + 1, __ATOMIC_RELAXED, __HIP_MEMORY_SCOPE_AGENT);
      }

      // ---- stage this half's B (32 cols, 64KB) into LDS ----
      // NOTE: the vmcnt(0) here also drains the PREVIOUS half's state stores.
      {
        const char* sp = (const char*)browf(colbase + hb * 32 + scol, k) + skb0;
        u32x4 r0,r1,r2,r3,r4,r5,r6,r7;
        if (coh){
          asm volatile(
            "global_load_dwordx4 %0, %8, off sc0 sc1\n\t"
            "global_load_dwordx4 %1, %8, off offset:256 sc0 sc1\n\t"
            "global_load_dwordx4 %2, %8, off offset:512 sc0 sc1\n\t"
            "global_load_dwordx4 %3, %8, off offset:768 sc0 sc1\n\t"
            "global_load_dwordx4 %4, %8, off offset:1024 sc0 sc1\n\t"
            "global_load_dwordx4 %5, %8, off offset:1280 sc0 sc1\n\t"
            "global_load_dwordx4 %6, %8, off offset:1536 sc0 sc1\n\t"
            "global_load_dwordx4 %7, %8, off offset:1792 sc0 sc1\n\t"
            "s_waitcnt vmcnt(0)"
            : "=&v"(r0),"=&v"(r1),"=&v"(r2),"=&v"(r3),
              "=&v"(r4),"=&v"(r5),"=&v"(r6),"=&v"(r7)
            : "v"(sp) : "memory");
        } else {
          asm volatile(
            "global_load_dwordx4 %0, %8, off\n\t"
            "global_load_dwordx4 %1, %8, off offset:256\n\t"
            "global_load_dwordx4 %2, %8, off offset:512\n\t"
            "global_load_dwordx4 %3, %8, off offset:768\n\t"
            "global_load_dwordx4 %4, %8, off offset:1024\n\t"
            "global_load_dwordx4 %5, %8, off offset:1280\n\t"
            "global_load_dwordx4 %6, %8, off offset:1536\n\t"
            "global_load_dwordx4 %7, %8, off offset:1792\n\t"
            "s_waitcnt vmcnt(0)"
            : "=&v"(r0),"=&v"(r1),"=&v"(r2),"=&v"(r3),
              "=&v"(r4),"=&v"(r5),"=&v"(r6),"=&v"(r7)
            : "v"(sp) : "memory");
        }
        char* dst = &lds[hb * 65536 + scol * 2048];
        *(u32x4*)(dst + ((skb0 +    0) ^ sswz)) = r0;
        *(u32x4*)(dst + ((skb0 +  256) ^ sswz)) = r1;
        *(u32x4*)(dst + ((skb0 +  512) ^ sswz)) = r2;
        *(u32x4*)(dst + ((skb0 +  768) ^ sswz)) = r3;
        *(u32x4*)(dst + ((skb0 + 1024) ^ sswz)) = r4;
        *(u32x4*)(dst + ((skb0 + 1280) ^ sswz)) = r5;
        *(u32x4*)(dst + ((skb0 + 1536) ^ sswz)) = r6;
        *(u32x4*)(dst + ((skb0 + 1792) ^ sswz)) = r7;
      }
      __syncthreads();                        // B: half staged (+ prev stores drained)

      // signal "H0 of step k done" once all waves passed the drain above
      if (hb == 1 && tid == 0 && (k + 1) < STEPS){
        unsigned* fw = gflags + rwg;
        unsigned fv = (unsigned)(2 * k + 1);
        asm volatile("global_store_dword %0, %1, off sc0 sc1"
                     :: "v"(fw), "v"(fv) : "memory");
      }

      // ---- MFMA K-loop ----
      f32x4 acc00 = {0,0,0,0}, acc01 = {0,0,0,0}, acc10 = {0,0,0,0}, acc11 = {0,0,0,0};
      const char* bbase = &lds[hb * 65536 + colb0];
      #pragma unroll
      for (int i = 0; i < 17; ++i){
        if (i < NL){
          int kb = (KB + i) * 64 + l4b;
          const short8 b0 = *(const short8*)(bbase + ((kb) ^ bswz));
          const short8 b1 = *(const short8*)(bbase + 32768 + ((kb) ^ bswz));
          acc00 = __builtin_amdgcn_mfma_f32_16x16x32_bf16(a0[i], b0, acc00, 0, 0, 0);
          acc01 = __builtin_amdgcn_mfma_f32_16x16x32_bf16(a0[i], b1, acc01, 0, 0, 0);
          acc10 = __builtin_amdgcn_mfma_f32_16x16x32_bf16(a1[i], b0, acc10, 0, 0, 0);
          acc11 = __builtin_amdgcn_mfma_f32_16x16x32_bf16(a1[i], b1, acc11, 0, 0, 0);
        }
      }
      if (hi){
        u32x4 v0; v0.x=(unsigned)t00; v0.y=(unsigned)(t00>>32); v0.z=(unsigned)t01; v0.w=(unsigned)(t01>>32);
        u32x4 v1; v1.x=(unsigned)t10; v1.y=(unsigned)(t10>>32); v1.z=(unsigned)t11; v1.w=(unsigned)(t11>>32);
        const short8 b0 = __builtin_bit_cast(short8, v0);
        const short8 b1 = __builtin_bit_cast(short8, v1);
        acc00 = __builtin_amdgcn_mfma_f32_16x16x32_bf16(a0[15], b0, acc00, 0, 0, 0);
        acc01 = __builtin_amdgcn_mfma_f32_16x16x32_bf16(a0[15], b1, acc01, 0, 0, 0);
        acc10 = __builtin_amdgcn_mfma_f32_16x16x32_bf16(a1[15], b0, acc10, 0, 0, 0);
        acc11 = __builtin_amdgcn_mfma_f32_16x16x32_bf16(a1[15], b1, acc11, 0, 0, 0);
      }

      // ---- cross-pair K-reduction (reuse this half's LDS region) ----
      __syncthreads();                        // C
      {
        char* eb = &lds[hb * 65536];
        *(f32x4*)(eb + wv * 1024 + xsw)        = hi ? acc00 : acc10;
        *(f32x4*)(eb + 8192 + wv * 1024 + xsw) = hi ? acc01 : acc11;
      }
      __syncthreads();                        // D
      {
        const char* eb = &lds[hb * 65536];
        f32x4 p0 = *(const f32x4*)(eb + (wv ^ 1) * 1024 + xsw);
        f32x4 p1 = *(const f32x4*)(eb + 8192 + (wv ^ 1) * 1024 + xsw);
        f32x4 f0 = (hi ? acc10 : acc00) + p0;
        f32x4 f1 = (hi ? acc11 : acc01) + p1;
        const int rowb = rbase + hi * 16 + l4 * 4;
        #pragma unroll
        for (int ct = 0; ct < 2; ++ct){
          f32x4 z = ct ? f1 : f0;
          float s0 = fast_tanh(z[0]), s1 = fast_tanh(z[1]);
          float s2 = fast_tanh(z[2]), s3 = fast_tanh(z[3]);
          unsigned long long pk = (unsigned long long)f2bf(s0)
            | ((unsigned long long)f2bf(s1) << 16)
            | ((unsigned long long)f2bf(s2) << 32)
            | ((unsigned long long)f2bf(s3) << 48);
          int col = colbase + hb * 32 + ct * 16 + l15;
          short* wp = wrowf(col, k) + rowb;
          asm volatile("global_store_dwordx2 %0, %1, off sc0 sc1"
                       :: "v"(wp), "v"(pk) : "memory");
          if (!HIST && k >= WARM){
            int tk = col * LCH + k - WARM;
            float* op = out + (size_t)rowb * T_LEN + tk;
            op[0] = s0; op[(size_t)T_LEN] = s1;
            op[(size_t)2 * T_LEN] = s2; op[(size_t)3 * T_LEN] = s3;
          }
        }
      }

      // ---- x for next step (this half's cols; rwg0 only) ----
      if (rwg == 0 && (tid >> 5) == hb && tid < 64 && (k + 1) < STEPS){
        int col = colbase + tid;
        short* xr = wrowf(col, k) + 1024;
        int tn = col * LCH + (k + 1) - WARM;
        u32x4 xv = {0,0,0,0};
        if (tn >= 0){
          const float4 A4 = *(const float4*)(inputs + (size_t)tn * 8);
          const float4 B4 = *(const float4*)(inputs + (size_t)tn * 8 + 4);
          xv.x = f2bf(A4.x) | ((unsigned)f2bf(A4.y) << 16);
          xv.y = f2bf(A4.z) | ((unsigned)f2bf(A4.w) << 16);
          xv.z = f2bf(B4.x) | ((unsigned)f2bf(B4.y) << 16);
          xv.w = f2bf(B4.z) | ((unsigned)f2bf(B4.w) << 16);
        }
        asm volatile("global_store_dwordx4 %0, %1, off sc0 sc1"
                     :: "v"(xr), "v"(xv) : "memory");
      }
      // H0: stores left in flight (drained by H1's staging vmcnt(0)).
    }

    // ---- end of step: drain H1 stores, signal 2k+2 ----
    asm volatile("s_waitcnt vmcnt(0)" ::: "memory");
    __syncthreads();                          // E
    if (tid == 0 && (k + 1) < STEPS){
      unsigned* fw = gflags + rwg;
      unsigned fv = (unsigned)(2 * k + 2);
      asm volatile("global_store_dword %0, %1, off sc0 sc1"
                   :: "v"(fw), "v"(fv) : "memory");
    }
  }
}

extern "C" void kernel_launch(void* const* d_in, const int* in_sizes, int n_in,
                              void* d_out, int out_size, void* d_ws, size_t ws_size,
                              hipStream_t stream)
{
  (void)in_sizes; (void)n_in; (void)out_size;
  const float* inputs = (const float*)d_in[0];
  const float* Win    = (const float*)d_in[1];
  const float* Wres   = (const float*)d_in[2];
  float* out = (float*)d_out;
  char* ws = (char*)d_ws;

  short*    Wext = (short*)(ws);                       // 2,162,688 B
  unsigned* cnt  = (unsigned*)(ws + 2162688);          // 32 groups x 64B
  char*     data = ws + 2166784;
  short*    hist = (short*)data;                       // 65536*1056*2 = 138,412,032 B
  short*    S0   = (short*)data;                       // !HIST: 2048*1056*2 B
  short*    S1   = (short*)(data + 4325376);
  const bool hist_ok = ws_size >= (2166784ull + 138412032ull);

  hipLaunchKernelGGL(k_build_wext, dim3(4224), dim3(256), 0, stream, Wres, Win, Wext);
  hipLaunchKernelGGL(k_xrows,      dim3(256),  dim3(256), 0, stream, inputs, out);
  if (hist_ok){
    hipLaunchKernelGGL(k_zero_init, dim3(4096), dim3(256), 0, stream,
                       hist + KE, (size_t)LCH * KE);
    hipLaunchKernelGGL(k_init_x,    dim3(8),    dim3(256), 0, stream,
                       inputs, hist + KE + 1024, (size_t)LCH * KE, cnt);
    hipLaunchKernelGGL((k_esn<true>),  dim3(RWG * NGRP), dim3(512), LDSB, stream,
                       inputs, Wext, S0, S1, hist, cnt, out);
    hipLaunchKernelGGL(k_transpose, dim3(1024, 16), dim3(256), 0, stream, hist, out);
  } else {
    hipLaunchKernelGGL(k_zero_init, dim3(4096), dim3(256), 0, stream,
                       S0, (size_t)KE);
    hipLaunchKernelGGL(k_init_x,    dim3(8),    dim3(256), 0, stream,
                       inputs, S0 + 1024, (size_t)KE, cnt);
    hipLaunchKernelGGL((k_esn<false>), dim3(RWG * NGRP), dim3(512), LDSB, stream,
                       inputs, Wext, S0, S1, hist, cnt, out);
  }
}